// Round 1
// 388.397 us; speedup vs baseline: 1.0228x; 1.0228x over previous
//
#include <hip/hip_runtime.h>

#define D_MODEL 2048
#define SEQ 2048
#define BATCH 2
#define NH 16
#define HD 128
#define MTOT 4096   // BATCH*SEQ
#define NQKV 6144   // 3*D_MODEL
#define QSTRIDE 4096  // QK buffer row stride (Q cols 0..2047, K cols 2048..4095)

// 1/sqrt(128) * log2(e)
static constexpr float SCALE_LOG2E = 0.08838834764831845f * 1.4426950408889634f;

typedef __bf16 bf16x8 __attribute__((ext_vector_type(8)));
typedef _Float16 f16x4 __attribute__((ext_vector_type(4)));
typedef float f32x4 __attribute__((ext_vector_type(4)));

__device__ inline unsigned short f2bf(float f) {
  unsigned int u = __builtin_bit_cast(unsigned int, f);
  u += 0x7fffu + ((u >> 16) & 1u);
  return (unsigned short)(u >> 16);
}

__device__ inline float fast_exp2(float x) {
#if __has_builtin(__builtin_amdgcn_exp2f)
  return __builtin_amdgcn_exp2f(x);
#else
  return exp2f(x);
#endif
}

__device__ inline void gload_lds16(const void* g, void* s) {
  __builtin_amdgcn_global_load_lds(
      (__attribute__((address_space(1))) void*)g,
      (__attribute__((address_space(3))) void*)s, 16, 0, 0);
}

// ---------------- fused fp32 -> bf16 conversion (all 5 inputs) -------------
__global__ __launch_bounds__(256) void cvt_all(
    const float* __restrict__ x, const float* __restrict__ wq,
    const float* __restrict__ wk, const float* __restrict__ wv,
    const float* __restrict__ wo, unsigned short* __restrict__ xb,
    unsigned short* __restrict__ wqkv, unsigned short* __restrict__ wob) {
  const int y = blockIdx.y;
  const float* src;
  unsigned short* dst;
  int n4;
  if (y == 0) { src = x; dst = xb; n4 = MTOT * D_MODEL / 4; }
  else if (y == 4) { src = wo; dst = wob; n4 = D_MODEL * D_MODEL / 4; }
  else {
    src = (y == 1) ? wq : (y == 2) ? wk : wv;
    dst = wqkv + (size_t)(y - 1) * D_MODEL * D_MODEL;
    n4 = D_MODEL * D_MODEL / 4;
  }
  int i = blockIdx.x * 256 + threadIdx.x;
  if (i < n4) {
    float4 v = ((const float4*)src)[i];
    ushort4 o;
    o.x = f2bf(v.x); o.y = f2bf(v.y); o.z = f2bf(v.z); o.w = f2bf(v.w);
    ((ushort4*)dst)[i] = o;
  }
}

// ---------------- fused QKV GEMM: 256x256 tile, 8-phase counted-vmcnt ------
// C[4096,6144] = A[4096,2048] * B[6144,2048]^T.
// 8 waves (2Mx4N), BK=64, LDS 128KB = 2 dbuf x (A 32K + B 32K).
// Per iteration: 2 K-tiles, 8 phases; each phase = {ds_read subtile || stage
// one 128-row half-tile via global_load_lds} -> s_barrier -> setprio-wrapped
// 16 MFMA -> s_barrier.  vmcnt(4) ONLY at phase 3/7 ends (loads stay in
// flight across barriers).  LDS swizzle: chunk ^= row&7 (128B rows, <=2-way),
// applied by pre-swizzling the global source address (linear gload_lds dest).
// Q/K cols (n<4096) -> bf16 QK buffer; V cols -> transposed f16 Vt[bh][d][s].
__global__ __launch_bounds__(512, 2) void gemm_qkv(
    const unsigned short* __restrict__ A, const unsigned short* __restrict__ B,
    unsigned short* __restrict__ QK, unsigned short* __restrict__ Vt) {
  extern __shared__ __align__(16) char smem[];
  const int K = D_MODEL;
  const int tid = threadIdx.x;
  const int lane = tid & 63;
  const int wave = tid >> 6;
  const int quad = lane >> 4;
  const int l15 = lane & 15;
  const int bid = blockIdx.x;
  const int tm = bid / (NQKV / 256);
  const int tn = bid % (NQKV / 256);
  const int m0 = tm * 256;
  const int n0 = tn * 256;
  const int wm = wave >> 2;  // 0..1
  const int wn = wave & 3;   // 0..3

  // ---- staging: thread's 2 loads per half-tile; source pre-swizzled ----
  // LDS linear dest (row, slot): row = 8*(2*wave+l) + lane>>3, slot = lane&7.
  // slot holds global chunk = slot ^ (row&7) = (lane&7) ^ (lane>>3).
  const int srow = wave * 16 + (lane >> 3);
  const int cch = ((lane & 7) ^ (lane >> 3)) * 8;
  const unsigned short* As0 = A + (size_t)(m0 + srow) * K + cch;
  const unsigned short* As1 = As0 + (size_t)8 * K;
  const unsigned short* Bs0 = B + (size_t)(n0 + srow) * K + cch;
  const unsigned short* Bs1 = Bs0 + (size_t)8 * K;
  const size_t HS = (size_t)128 * K;  // +128 rows (half 1)
  char* ldst = smem + wave * 2048;    // wave-uniform LDS staging base

#define STAGE(s0, s1, kofs, ldsofs)                       \
  do {                                                    \
    gload_lds16((s0) + (kofs), ldst + (ldsofs));          \
    gload_lds16((s1) + (kofs), ldst + (ldsofs) + 1024);   \
  } while (0)

  // ---- fragment reads: row r -> byte r*128 + ((chunk ^ (r&7))*16) ----
  const int arow = (wm * 128 + l15) * 128;
  const int brow = (wn * 64 + l15) * 128;
  const int sk0 = (quad ^ (l15 & 7)) * 16;        // k-step 0, chunk = quad
  const int sk1 = ((4 + quad) ^ (l15 & 7)) * 16;  // k-step 1, chunk = 4+quad

  f32x4 acc[8][4] = {};
  bf16x8 a[4][2], bl[2][2], bh[2][2];

#define LDA(p, mb)                                                             \
  _Pragma("unroll") for (int mi = 0; mi < 4; mi++) {                           \
    a[mi][0] = *(const bf16x8*)(smem + (p) * 65536 + arow + ((mb) + mi) * 2048 + sk0); \
    a[mi][1] = *(const bf16x8*)(smem + (p) * 65536 + arow + ((mb) + mi) * 2048 + sk1); \
  }
#define LDB(p, B_, nb)                                                         \
  _Pragma("unroll") for (int ni = 0; ni < 2; ni++) {                           \
    B_[ni][0] = *(const bf16x8*)(smem + (p) * 65536 + 32768 + brow + ((nb) + ni) * 2048 + sk0); \
    B_[ni][1] = *(const bf16x8*)(smem + (p) * 65536 + 32768 + brow + ((nb) + ni) * 2048 + sk1); \
  }
#define MMA(mh, B_, nh)                                                        \
  _Pragma("unroll") for (int mi = 0; mi < 4; mi++)                             \
  _Pragma("unroll") for (int ni = 0; ni < 2; ni++) {                           \
    acc[(mh) * 4 + mi][(nh) * 2 + ni] = __builtin_amdgcn_mfma_f32_16x16x32_bf16( \
        a[mi][0], B_[ni][0], acc[(mh) * 4 + mi][(nh) * 2 + ni], 0, 0, 0);      \
    acc[(mh) * 4 + mi][(nh) * 2 + ni] = __builtin_amdgcn_mfma_f32_16x16x32_bf16( \
        a[mi][1], B_[ni][1], acc[(mh) * 4 + mi][(nh) * 2 + ni], 0, 0, 0);      \
  }
#define BARX() __builtin_amdgcn_s_barrier()
#define PRIO(x) __builtin_amdgcn_s_setprio(x)
#define VMCNT4() asm volatile("s_waitcnt vmcnt(4)" ::: "memory")

  // ---- prologue: tile0 full (A0,A1,B0,B1) + tile1 (B0,B1) ----
  STAGE(As0, As1, 0, 0);
  STAGE(As0 + HS, As1 + HS, 0, 16384);
  STAGE(Bs0, Bs1, 0, 32768);
  STAGE(Bs0 + HS, Bs1 + HS, 0, 49152);
  STAGE(Bs0, Bs1, 64, 65536 + 32768);
  STAGE(Bs0 + HS, Bs1 + HS, 64, 65536 + 49152);
  VMCNT4();  // tile0 complete; tile1 B halves (4 loads) in flight
  BARX();

  // iteration i computes K-tiles 2i (buf0) and 2i+1 (buf1).
  // stage schedule (region free >=1 phase after last read):
  //  ph0:A0(2i+1)->buf1  ph1:A1(2i+1)->buf1  ph2:B0(2i+2)->buf0
  //  ph3:B1(2i+2)->buf0  ph4:A0(2i+2)->buf0  ph5:A1(2i+2)->buf0
  //  ph6:B0(2i+3)->buf1  ph7:B1(2i+3)->buf1
  for (int i = 0; i < K / 128; ++i) {
    const int kO = ((2 * i + 1) & 31) * 64;   // odd tile cols
    const int kE = ((2 * i + 2) & 31) * 64;   // next even tile (wraps on tail)
    const int kO3 = ((2 * i + 3) & 31) * 64;  // next odd tile (wraps on tail)
    // phase 0: read buf0 A-lo + B-lo (12 ds_reads)
    LDA(0, 0); LDB(0, bl, 0);
    STAGE(As0, As1, kO, 65536);
    BARX(); PRIO(1); MMA(0, bl, 0); PRIO(0); BARX();
    // phase 1: read buf0 B-hi
    LDB(0, bh, 2);
    STAGE(As0 + HS, As1 + HS, kO, 65536 + 16384);
    BARX(); PRIO(1); MMA(0, bh, 1); PRIO(0); BARX();
    // phase 2: read buf0 A-hi
    LDA(0, 4);
    STAGE(Bs0, Bs1, kE, 32768);
    BARX(); PRIO(1); MMA(1, bl, 0); PRIO(0); BARX();
    // phase 3: no reads; counted drain for buf1 A halves
    STAGE(Bs0 + HS, Bs1 + HS, kE, 49152);
    BARX(); PRIO(1); MMA(1, bh, 1); PRIO(0); VMCNT4(); BARX();
    // phase 4: read buf1 A-lo + B-lo
    LDA(1, 0); LDB(1, bl, 0);
    STAGE(As0, As1, kE, 0);
    BARX(); PRIO(1); MMA(0, bl, 0); PRIO(0); BARX();
    // phase 5: read buf1 B-hi
    LDB(1, bh, 2);
    STAGE(As0 + HS, As1 + HS, kE, 16384);
    BARX(); PRIO(1); MMA(0, bh, 1); PRIO(0); BARX();
    // phase 6: read buf1 A-hi
    LDA(1, 4);
    STAGE(Bs0, Bs1, kO3, 65536 + 32768);
    BARX(); PRIO(1); MMA(1, bl, 0); PRIO(0); BARX();
    // phase 7: no reads; counted drain for buf0 (tile 2i+2)
    STAGE(Bs0 + HS, Bs1 + HS, kO3, 65536 + 49152);
    BARX(); PRIO(1); MMA(1, bh, 1); PRIO(0); VMCNT4(); BARX();
  }

  const int er = quad * 4;
  if (n0 < 4096) {
    // Q/K: plain bf16 store, row stride 4096
#pragma unroll
    for (int mi = 0; mi < 8; mi++)
#pragma unroll
      for (int ni = 0; ni < 4; ni++) {
        const int mm = m0 + wm * 128 + mi * 16 + er;
        const int nn = n0 + wn * 64 + ni * 16 + l15;
#pragma unroll
        for (int r = 0; r < 4; r++)
          QK[(size_t)(mm + r) * QSTRIDE + nn] = f2bf(acc[mi][ni][r]);
      }
  } else {
    // V: transpose via reused LDS ([128][264] f16 per head), f16 -> Vt[bh][d][s]
    asm volatile("s_waitcnt vmcnt(0)" ::: "memory");
    BARX();
    unsigned short* T = (unsigned short*)smem;
    const int vcol0 = n0 - 4096;
    const int bb = m0 >> 11;
    const int h0 = vcol0 >> 7;  // even head; tile covers heads h0, h0+1
    const int sbase = m0 & (SEQ - 1);
#pragma unroll
    for (int p = 0; p < 2; p++) {
      if (p) BARX();  // pass-0 reads done before overwrite
      if ((wn >> 1) == p) {
#pragma unroll
        for (int mi = 0; mi < 8; mi++)
#pragma unroll
          for (int ni = 0; ni < 4; ni++) {
            const int d = (wn & 1) * 64 + ni * 16 + l15;
            const int s = wm * 128 + mi * 16 + er;
            f16x4 hv;
#pragma unroll
            for (int r = 0; r < 4; r++) hv[r] = (_Float16)acc[mi][ni][r];
            *(f16x4*)(T + d * 264 + s) = hv;
          }
      }
      BARX();
      const int d = tid >> 2;
      const int sc = (tid & 3) * 64;
      const size_t vrow = ((size_t)(bb * NH + h0 + p) * HD + d) * SEQ + sbase + sc;
#pragma unroll
      for (int j = 0; j < 8; j++) {
        float4 c4 = *(const float4*)(T + d * 264 + sc + j * 8);
        *(float4*)(Vt + vrow + j * 8) = c4;
      }
    }
  }
#undef STAGE
#undef LDA
#undef LDB
#undef MMA
#undef BARX
#undef PRIO
#undef VMCNT4
}

// ---------------- output-projection GEMM: 128x64 tiles, 4 blocks/CU --------
// 1024 blocks (vs 512 for 128x128): co-resident-block overlap hides the
// barrier drain (measured lever: 512blk=455TF, 1536blk=753TF on this chip).
__global__ __launch_bounds__(256, 4) void gemm_out(
    const unsigned short* __restrict__ A, const unsigned short* __restrict__ B,
    float* __restrict__ C, int M, int N, int K) {
  __shared__ __align__(16) unsigned short As[128 * 32];
  __shared__ __align__(16) unsigned short Bs[64 * 32];
  const int tid = threadIdx.x;
  const int lane = tid & 63;
  const int wave = tid >> 6;
  const int quad = lane >> 4;
  const int l15 = lane & 15;
  const int m0 = blockIdx.y * 128;
  const int n0 = blockIdx.x * 64;
  const int wm = (wave >> 1) * 64;
  const int wn = (wave & 1) * 32;

  const int srow = lane >> 2;
  const int sk = (((lane & 3) ^ (srow & 3))) * 8;  // XOR swizzle
  const unsigned short* Ag0 = A + (size_t)(m0 + wave * 32 + srow) * K + sk;
  const unsigned short* Ag1 = A + (size_t)(m0 + wave * 32 + 16 + srow) * K + sk;
  unsigned short* lA0 = As + (wave * 2) * 512;
  unsigned short* lA1 = As + (wave * 2 + 1) * 512;
  const unsigned short* Bg = B + (size_t)(n0 + wave * 16 + srow) * K + sk;
  unsigned short* lB = Bs + wave * 512;

  f32x4 acc[4][2] = {};
  const int axor = (quad ^ (l15 & 3)) * 8;

  for (int k0 = 0; k0 < K; k0 += 32) {
    __syncthreads();
    gload_lds16(Ag0 + k0, lA0);
    gload_lds16(Ag1 + k0, lA1);
    gload_lds16(Bg + k0, lB);
    __builtin_amdgcn_s_waitcnt(0);
    __syncthreads();
    bf16x8 a[4], b[2];
#pragma unroll
    for (int i = 0; i < 4; i++)
      a[i] = *(const bf16x8*)(As + (wm + i * 16 + l15) * 32 + axor);
#pragma unroll
    for (int j = 0; j < 2; j++)
      b[j] = *(const bf16x8*)(Bs + (wn + j * 16 + l15) * 32 + axor);
#pragma unroll
    for (int i = 0; i < 4; i++)
#pragma unroll
      for (int j = 0; j < 2; j++)
        acc[i][j] = __builtin_amdgcn_mfma_f32_16x16x32_bf16(a[i], b[j], acc[i][j], 0, 0, 0);
  }

  const int er = quad * 4;
  const int ec = l15;
#pragma unroll
  for (int i = 0; i < 4; i++)
#pragma unroll
    for (int j = 0; j < 2; j++) {
      const int mm = m0 + wm + i * 16 + er;
      const int nn = n0 + wn + j * 16 + ec;
#pragma unroll
      for (int r = 0; r < 4; r++)
        C[(size_t)(mm + r) * N + nn] = acc[i][j][r];
    }
}

// ---------------- flash attention v3 (XCD-swizzled) ------------------------
__global__ __launch_bounds__(256, 2) void flash_attn(
    const unsigned short* __restrict__ QK, const unsigned short* __restrict__ Vt,
    unsigned short* __restrict__ Og) {
  __shared__ __align__(16) unsigned short Ks[2][64 * 128];
  __shared__ __align__(16) unsigned short Vs[2][128 * 64];
  const int tid = threadIdx.x;
  const int lane = tid & 63;
  const int wave = tid >> 6;
  const int quad = lane >> 4;
  const int l15 = lane & 15;
  const int id = blockIdx.x;
  const int xr = id & 7;
  const int kk = id >> 3;
  const int bh = xr * 4 + (kk >> 4);
  const int b = bh >> 4, h = bh & 15;
  const int q0 = (kk & 15) * 128;

  const size_t kbase = (size_t)(b * SEQ) * QSTRIDE + D_MODEL + h * HD;
  const size_t vbase = (size_t)bh * HD * SEQ;

  bf16x8 qf[2][4];
#pragma unroll
  for (int t = 0; t < 2; t++)
#pragma unroll
    for (int kc = 0; kc < 4; kc++)
      qf[t][kc] = *(const bf16x8*)(QK + (size_t)(b * SEQ + q0 + wave * 32 + t * 16 + l15) * QSTRIDE +
                                   h * HD + kc * 32 + quad * 8);

  const unsigned short* kg[4];
  const unsigned short* vg[4];
  int klofs[4], vlofs[4];
#pragma unroll
  for (int i = 0; i < 4; i++) {
    int krow = wave * 16 + i * 4 + quad;
    int kc_ = l15 ^ (i * 4 + quad);
    kg[i] = QK + kbase + (size_t)krow * QSTRIDE + kc_ * 8;
    klofs[i] = (wave * 16 + i * 4) * 128;
    int vrow = wave * 32 + i * 8 + (lane >> 3);
    int vc_ = (lane & 7) ^ (lane >> 3);
    vg[i] = Vt + vbase + (size_t)vrow * SEQ + vc_ * 8;
    vlofs[i] = (wave * 32 + i * 8) * 64;
  }

#pragma unroll
  for (int i = 0; i < 4; i++) gload_lds16(kg[i], &Ks[0][klofs[i]]);
#pragma unroll
  for (int i = 0; i < 4; i++) gload_lds16(vg[i], &Vs[0][vlofs[i]]);
#pragma unroll
  for (int i = 0; i < 4; i++) { kg[i] += 64 * QSTRIDE; vg[i] += 64; }
  __builtin_amdgcn_s_waitcnt(0);
  __syncthreads();

  float lsum[2] = {0.f, 0.f};
  f32x4 Oa[2][8] = {};

  for (int it = 0; it < SEQ / 64; ++it) {
    const int cur = it & 1;
    if (it < SEQ / 64 - 1) {
#pragma unroll
      for (int i = 0; i < 4; i++) gload_lds16(kg[i], &Ks[cur ^ 1][klofs[i]]);
#pragma unroll
      for (int i = 0; i < 4; i++) gload_lds16(vg[i], &Vs[cur ^ 1][vlofs[i]]);
#pragma unroll
      for (int i = 0; i < 4; i++) { kg[i] += 64 * QSTRIDE; vg[i] += 64; }
    }

    const unsigned short* kb = &Ks[cur][0];
    f32x4 sacc[2][4] = {};
#pragma unroll
    for (int js = 0; js < 4; js++)
#pragma unroll
      for (int kc = 0; kc < 4; kc++) {
        bf16x8 kf = *(const bf16x8*)(kb + (js * 16 + l15) * 128 + (((kc * 4 + quad) ^ l15) * 8));
        sacc[0][js] = __builtin_amdgcn_mfma_f32_16x16x32_bf16(kf, qf[0][kc], sacc[0][js], 0, 0, 0);
        sacc[1][js] = __builtin_amdgcn_mfma_f32_16x16x32_bf16(kf, qf[1][kc], sacc[1][js], 0, 0, 0);
      }

    f16x4 pb[2][4];
#pragma unroll
    for (int t = 0; t < 2; t++)
#pragma unroll
      for (int js = 0; js < 4; js++)
#pragma unroll
        for (int r = 0; r < 4; r++) {
          float p = fast_exp2(sacc[t][js][r] * SCALE_LOG2E);
          lsum[t] += p;
          pb[t][js][r] = (_Float16)p;
        }

    const unsigned short* vb_ = &Vs[cur][0];
#pragma unroll
    for (int jt = 0; jt < 8; jt++)
#pragma unroll
      for (int js = 0; js < 4; js++) {
        f16x4 vf = *(const f16x4*)(vb_ + (jt * 16 + l15) * 64 +
                                   (((js * 2 + (quad >> 1)) ^ (lane & 7)) * 8) + (quad & 1) * 4);
        Oa[0][jt] = __builtin_amdgcn_mfma_f32_16x16x16f16(vf, pb[0][js], Oa[0][jt], 0, 0, 0);
        Oa[1][jt] = __builtin_amdgcn_mfma_f32_16x16x16f16(vf, pb[1][js], Oa[1][jt], 0, 0, 0);
      }

    __builtin_amdgcn_s_waitcnt(0);
    __syncthreads();
  }

  float inv[2];
#pragma unroll
  for (int t = 0; t < 2; t++) {
    float s = lsum[t];
    s += __shfl_xor(s, 16);
    s += __shfl_xor(s, 32);
    inv[t] = 1.0f / s;
  }

#pragma unroll
  for (int t = 0; t < 2; t++) {
    const size_t rowbase = (size_t)(b * SEQ + q0 + wave * 32 + t * 16 + l15) * D_MODEL + h * HD;
#pragma unroll
    for (int jt = 0; jt < 8; jt++) {
      ushort4 o;
      o.x = f2bf(Oa[t][jt][0] * inv[t]);
      o.y = f2bf(Oa[t][jt][1] * inv[t]);
      o.z = f2bf(Oa[t][jt][2] * inv[t]);
      o.w = f2bf(Oa[t][jt][3] * inv[t]);
      *(ushort4*)(Og + rowbase + jt * 16 + quad * 4) = o;
    }
  }
}

// ---------------- launcher ----------------
extern "C" void kernel_launch(void* const* d_in, const int* in_sizes, int n_in,
                              void* d_out, int out_size, void* d_ws, size_t ws_size,
                              hipStream_t stream) {
  const float* x = (const float*)d_in[0];
  const float* wq = (const float*)d_in[1];
  const float* wk = (const float*)d_in[2];
  const float* wv = (const float*)d_in[3];
  const float* wo = (const float*)d_in[4];
  float* out = (float*)d_out;
  char* ws = (char*)d_ws;
  const size_t MB = 1u << 20;
  if (ws_size < 96 * MB) return;

  unsigned short* xb = (unsigned short*)(ws);             // 16 MB (reused as Ab)
  unsigned short* wqkv = (unsigned short*)(ws + 16 * MB); // 24 MB [6144,2048]
  unsigned short* wob = (unsigned short*)(ws + 40 * MB);  // 8 MB
  unsigned short* QKb = (unsigned short*)(ws + 48 * MB);  // 32 MB [4096,4096]
  unsigned short* Vtb = (unsigned short*)(ws + 80 * MB);  // 16 MB f16
  unsigned short* Ab = xb;

  static int lds_set = 0;
  if (!lds_set) {
    hipFuncSetAttribute((const void*)gemm_qkv,
                        hipFuncAttributeMaxDynamicSharedMemorySize, 131072);
    lds_set = 1;
  }

  cvt_all<<<dim3(8192, 5), 256, 0, stream>>>(x, wq, wk, wv, wo, xb, wqkv, wob);

  gemm_qkv<<<dim3((NQKV / 256) * (MTOT / 256)), 512, 131072, stream>>>(xb, wqkv, QKb, Vtb);

  flash_attn<<<512, 256, 0, stream>>>(QKb, Vtb, Ab);

  gemm_out<<<dim3(D_MODEL / 64, MTOT / 128), 256, 0, stream>>>(Ab, wob, out, MTOT, D_MODEL, D_MODEL);
}

// Round 2
// 359.901 us; speedup vs baseline: 1.1038x; 1.0792x over previous
//
#include <hip/hip_runtime.h>

#define D_MODEL 2048
#define SEQ 2048
#define BATCH 2
#define NH 16
#define HD 128
#define MTOT 4096   // BATCH*SEQ
#define NQKV 6144   // 3*D_MODEL
#define QSTRIDE 4096  // QK buffer row stride (Q cols 0..2047, K cols 2048..4095)

// 1/sqrt(128) * log2(e)
static constexpr float SCALE_LOG2E = 0.08838834764831845f * 1.4426950408889634f;

typedef __bf16 bf16x8 __attribute__((ext_vector_type(8)));
typedef _Float16 f16x4 __attribute__((ext_vector_type(4)));
typedef float f32x4 __attribute__((ext_vector_type(4)));

__device__ inline unsigned short f2bf(float f) {
  unsigned int u = __builtin_bit_cast(unsigned int, f);
  u += 0x7fffu + ((u >> 16) & 1u);
  return (unsigned short)(u >> 16);
}

__device__ inline float fast_exp2(float x) {
#if __has_builtin(__builtin_amdgcn_exp2f)
  return __builtin_amdgcn_exp2f(x);
#else
  return exp2f(x);
#endif
}

__device__ inline void gload_lds16(const void* g, void* s) {
  __builtin_amdgcn_global_load_lds(
      (__attribute__((address_space(1))) void*)g,
      (__attribute__((address_space(3))) void*)s, 16, 0, 0);
}

// ---------------- fused fp32 -> bf16 conversion (all 5 inputs) -------------
__global__ __launch_bounds__(256) void cvt_all(
    const float* __restrict__ x, const float* __restrict__ wq,
    const float* __restrict__ wk, const float* __restrict__ wv,
    const float* __restrict__ wo, unsigned short* __restrict__ xb,
    unsigned short* __restrict__ wqkv, unsigned short* __restrict__ wob) {
  const int y = blockIdx.y;
  const float* src;
  unsigned short* dst;
  int n4;
  if (y == 0) { src = x; dst = xb; n4 = MTOT * D_MODEL / 4; }
  else if (y == 4) { src = wo; dst = wob; n4 = D_MODEL * D_MODEL / 4; }
  else {
    src = (y == 1) ? wq : (y == 2) ? wk : wv;
    dst = wqkv + (size_t)(y - 1) * D_MODEL * D_MODEL;
    n4 = D_MODEL * D_MODEL / 4;
  }
  int i = blockIdx.x * 256 + threadIdx.x;
  if (i < n4) {
    float4 v = ((const float4*)src)[i];
    ushort4 o;
    o.x = f2bf(v.x); o.y = f2bf(v.y); o.z = f2bf(v.z); o.w = f2bf(v.w);
    ((ushort4*)dst)[i] = o;
  }
}

// ============================================================================
// Shared GEMM core: BM=256 x BN=128, BK=64, 8 waves (4M x 2N -> 64x64/wave),
// TRIPLE-buffered LDS (3 x 48KB = 144KB), 2 phases per K-tile:
//   phase = {ds_read frags || stage 3 units} -> s_barrier -> lgkmcnt(0) ->
//           sched_barrier -> setprio(1) 16xMFMA setprio(0) -> [vmcnt] barrier
// vmcnt(6) once per K-tile (leaves current tile's 6 stage-loads in flight ->
// each load gets ~2 K-tiles of latency cover).  LDS rows 128B, 8 chunks of
// 16B, chunk slot ^= row&7 (conflict-free), applied via pre-swizzled global
// source + linear global_load_lds dest.
// ============================================================================
#define GEMM_SETUP(Aptr, Bptr)                                                 \
  const int tid = threadIdx.x;                                                 \
  const int lane = tid & 63;                                                   \
  const int wave = tid >> 6;                                                   \
  const int quad = lane >> 4;                                                  \
  const int l15 = lane & 15;                                                   \
  const int wm = wave >> 1;                                                    \
  const int wn = wave & 1;                                                     \
  const unsigned short* Ag =                                                   \
      (Aptr) + (size_t)(m0 + wave * 8 + (lane >> 3)) * 2048 +                  \
      (size_t)(((lane & 7) ^ (lane >> 3)) * 8);                                \
  const unsigned short* Bg =                                                   \
      (Bptr) + (size_t)(n0 + wave * 8 + (lane >> 3)) * 2048 +                  \
      (size_t)(((lane & 7) ^ (lane >> 3)) * 8);                                \
  char* sd = smem + wave * 1024;                                               \
  const int arow0 = (wm * 64 + l15) * 128;                                     \
  const int brow0 = (wn * 64 + l15) * 128;                                     \
  const int sk0 = ((quad) ^ (l15 & 7)) * 16;                                   \
  const int sk1 = ((4 + quad) ^ (l15 & 7)) * 16;                               \
  f32x4 acc[4][4] = {};

// stage one 64-row unit (1 load/thread, 8KB) of tile tt into buffer NB
#define SA(tt, u, NB)                                                          \
  gload_lds16(Ag + (size_t)(u) * 64 * 2048 + (tt) * 64,                        \
              sd + (NB) * 49152 + (u) * 8192)
#define SB(tt, u, NB)                                                          \
  gload_lds16(Bg + (size_t)(u) * 64 * 2048 + (tt) * 64,                        \
              sd + (NB) * 49152 + 32768 + (u) * 8192)

#define RDA(dst, mi, CB)                                                       \
  dst[0] = *(const bf16x8*)(smem + (CB) * 49152 + arow0 + (mi) * 2048 + sk0);  \
  dst[1] = *(const bf16x8*)(smem + (CB) * 49152 + arow0 + (mi) * 2048 + sk1);
#define RDB(ni, CB)                                                            \
  bfr[ni][0] =                                                                 \
      *(const bf16x8*)(smem + (CB) * 49152 + 32768 + brow0 + (ni) * 2048 + sk0); \
  bfr[ni][1] =                                                                 \
      *(const bf16x8*)(smem + (CB) * 49152 + 32768 + brow0 + (ni) * 2048 + sk1);

#define MM2(mi, areg)                                                          \
  _Pragma("unroll") for (int ni_ = 0; ni_ < 4; ni_++) {                        \
    acc[mi][ni_] = __builtin_amdgcn_mfma_f32_16x16x32_bf16(                    \
        areg[0], bfr[ni_][0], acc[mi][ni_], 0, 0, 0);                          \
    acc[mi][ni_] = __builtin_amdgcn_mfma_f32_16x16x32_bf16(                    \
        areg[1], bfr[ni_][1], acc[mi][ni_], 0, 0, 0);                          \
  }

#define TILE(t, CB, NB, DOSTAGE, VMN)                                          \
  {                                                                            \
    bf16x8 af0[2], af1[2], af2[2], af3[2], bfr[4][2];                          \
    RDA(af0, 0, CB); RDA(af1, 1, CB);                                          \
    RDB(0, CB); RDB(1, CB); RDB(2, CB); RDB(3, CB);                            \
    if (DOSTAGE) { SA((t) + 2, 0, NB); SA((t) + 2, 1, NB); SB((t) + 2, 0, NB); } \
    __builtin_amdgcn_s_barrier();                                              \
    asm volatile("s_waitcnt lgkmcnt(0)" ::: "memory");                         \
    __builtin_amdgcn_sched_barrier(0);                                         \
    __builtin_amdgcn_s_setprio(1);                                             \
    MM2(0, af0); MM2(1, af1);                                                  \
    __builtin_amdgcn_s_setprio(0);                                             \
    __builtin_amdgcn_s_barrier();                                              \
    RDA(af2, 2, CB); RDA(af3, 3, CB);                                          \
    if (DOSTAGE) { SA((t) + 2, 2, NB); SA((t) + 2, 3, NB); SB((t) + 2, 1, NB); } \
    __builtin_amdgcn_s_barrier();                                              \
    asm volatile("s_waitcnt lgkmcnt(0)" ::: "memory");                         \
    __builtin_amdgcn_sched_barrier(0);                                         \
    __builtin_amdgcn_s_setprio(1);                                             \
    MM2(2, af2); MM2(3, af3);                                                  \
    __builtin_amdgcn_s_setprio(0);                                             \
    asm volatile("s_waitcnt vmcnt(" #VMN ")" ::: "memory");                    \
    __builtin_amdgcn_s_barrier();                                              \
  }

// K=2048 -> 32 K-tiles.  Prologue stages tiles 0,1; tile t stages t+2.
#define GEMM_KLOOP()                                                           \
  SA(0, 0, 0); SA(0, 1, 0); SA(0, 2, 0); SA(0, 3, 0); SB(0, 0, 0); SB(0, 1, 0);\
  SA(1, 0, 1); SA(1, 1, 1); SA(1, 2, 1); SA(1, 3, 1); SB(1, 0, 1); SB(1, 1, 1);\
  asm volatile("s_waitcnt vmcnt(6)" ::: "memory");                             \
  __builtin_amdgcn_s_barrier();                                                \
  for (int t = 0; t < 30; t += 3) {                                            \
    TILE(t + 0, 0, 2, 1, 6);                                                   \
    TILE(t + 1, 1, 0, 1, 6);                                                   \
    TILE(t + 2, 2, 1, 1, 6);                                                   \
  }                                                                            \
  TILE(30, 0, 2, 0, 0);                                                        \
  TILE(31, 1, 0, 0, 0);

// ---------------- fused QKV GEMM -------------------------------------------
// C[4096,6144] = A[4096,2048] * B[6144,2048]^T.  768 blocks = 3 exact rounds.
// BN=128 divides the Q/K|V boundary (4096), so every tile is pure.
__global__ __launch_bounds__(512, 2) void gemm_qkv(
    const unsigned short* __restrict__ A, const unsigned short* __restrict__ B,
    unsigned short* __restrict__ QK, unsigned short* __restrict__ Vt) {
  extern __shared__ __align__(16) char smem[];
  const int bid = blockIdx.x;
  const int wgid = (bid & 7) * 96 + (bid >> 3);  // bijective XCD swizzle (768%8==0)
  const int tm = wgid / 48;
  const int tn = wgid - tm * 48;
  const int m0 = tm * 256;
  const int n0 = tn * 128;
  GEMM_SETUP(A, B);
  GEMM_KLOOP();

  if (n0 < 4096) {
    // Q/K: plain bf16 store, row stride 4096
#pragma unroll
    for (int mi = 0; mi < 4; mi++)
#pragma unroll
      for (int ni = 0; ni < 4; ni++) {
        const int mm = m0 + wm * 64 + mi * 16 + quad * 4;
        const int nn = n0 + wn * 64 + ni * 16 + l15;
#pragma unroll
        for (int r = 0; r < 4; r++)
          QK[(size_t)(mm + r) * QSTRIDE + nn] = f2bf(acc[mi][ni][r]);
      }
  } else {
    // V: tile = one head's full 128 dims x 256 seq.  Transpose via LDS
    // ([128][264] f16, 67.6KB <= 144KB), f16 out -> Vt[bh][d][s].
    asm volatile("s_waitcnt vmcnt(0)" ::: "memory");
    __builtin_amdgcn_s_barrier();
    unsigned short* T = (unsigned short*)smem;
    const int h = (n0 - 4096) >> 7;
    const int bb = m0 >> 11;
    const int sbase = m0 & (SEQ - 1);
#pragma unroll
    for (int mi = 0; mi < 4; mi++)
#pragma unroll
      for (int ni = 0; ni < 4; ni++) {
        const int d = wn * 64 + ni * 16 + l15;
        const int s = wm * 64 + mi * 16 + quad * 4;
        f16x4 hv;
#pragma unroll
        for (int r = 0; r < 4; r++) hv[r] = (_Float16)acc[mi][ni][r];
        *(f16x4*)(T + d * 264 + s) = hv;
      }
    __builtin_amdgcn_s_barrier();
    const int d = tid >> 2;
    const int sc = (tid & 3) * 64;
    const size_t vrow = ((size_t)(bb * NH + h) * HD + d) * SEQ + sbase + sc;
#pragma unroll
    for (int j = 0; j < 8; j++) {
      float4 c4 = *(const float4*)(T + d * 264 + sc + j * 8);
      *(float4*)(Vt + vrow + j * 8) = c4;
    }
  }
}

// ---------------- output-projection GEMM -----------------------------------
// C[4096,2048] f32 = A[4096,2048] * B[2048,2048]^T.  256 blocks = 1 round.
__global__ __launch_bounds__(512, 2) void gemm_out(
    const unsigned short* __restrict__ A, const unsigned short* __restrict__ B,
    float* __restrict__ C) {
  extern __shared__ __align__(16) char smem[];
  const int bid = blockIdx.x;
  const int wgid = (bid & 7) * 32 + (bid >> 3);  // bijective (256%8==0)
  const int tm = wgid >> 4;
  const int tn = wgid & 15;
  const int m0 = tm * 256;
  const int n0 = tn * 128;
  GEMM_SETUP(A, B);
  GEMM_KLOOP();

#pragma unroll
  for (int mi = 0; mi < 4; mi++)
#pragma unroll
    for (int ni = 0; ni < 4; ni++) {
      const int mm = m0 + wm * 64 + mi * 16 + quad * 4;
      const int nn = n0 + wn * 64 + ni * 16 + l15;
#pragma unroll
      for (int r = 0; r < 4; r++)
        C[(size_t)(mm + r) * D_MODEL + nn] = acc[mi][ni][r];
    }
}

// ---------------- flash attention v3 (XCD-swizzled) ------------------------
__global__ __launch_bounds__(256, 2) void flash_attn(
    const unsigned short* __restrict__ QK, const unsigned short* __restrict__ Vt,
    unsigned short* __restrict__ Og) {
  __shared__ __align__(16) unsigned short Ks[2][64 * 128];
  __shared__ __align__(16) unsigned short Vs[2][128 * 64];
  const int tid = threadIdx.x;
  const int lane = tid & 63;
  const int wave = tid >> 6;
  const int quad = lane >> 4;
  const int l15 = lane & 15;
  const int id = blockIdx.x;
  const int xr = id & 7;
  const int kk = id >> 3;
  const int bh = xr * 4 + (kk >> 4);
  const int b = bh >> 4, h = bh & 15;
  const int q0 = (kk & 15) * 128;

  const size_t kbase = (size_t)(b * SEQ) * QSTRIDE + D_MODEL + h * HD;
  const size_t vbase = (size_t)bh * HD * SEQ;

  bf16x8 qf[2][4];
#pragma unroll
  for (int t = 0; t < 2; t++)
#pragma unroll
    for (int kc = 0; kc < 4; kc++)
      qf[t][kc] = *(const bf16x8*)(QK + (size_t)(b * SEQ + q0 + wave * 32 + t * 16 + l15) * QSTRIDE +
                                   h * HD + kc * 32 + quad * 8);

  const unsigned short* kg[4];
  const unsigned short* vg[4];
  int klofs[4], vlofs[4];
#pragma unroll
  for (int i = 0; i < 4; i++) {
    int krow = wave * 16 + i * 4 + quad;
    int kc_ = l15 ^ (i * 4 + quad);
    kg[i] = QK + kbase + (size_t)krow * QSTRIDE + kc_ * 8;
    klofs[i] = (wave * 16 + i * 4) * 128;
    int vrow = wave * 32 + i * 8 + (lane >> 3);
    int vc_ = (lane & 7) ^ (lane >> 3);
    vg[i] = Vt + vbase + (size_t)vrow * SEQ + vc_ * 8;
    vlofs[i] = (wave * 32 + i * 8) * 64;
  }

#pragma unroll
  for (int i = 0; i < 4; i++) gload_lds16(kg[i], &Ks[0][klofs[i]]);
#pragma unroll
  for (int i = 0; i < 4; i++) gload_lds16(vg[i], &Vs[0][vlofs[i]]);
#pragma unroll
  for (int i = 0; i < 4; i++) { kg[i] += 64 * QSTRIDE; vg[i] += 64; }
  __builtin_amdgcn_s_waitcnt(0);
  __syncthreads();

  float lsum[2] = {0.f, 0.f};
  f32x4 Oa[2][8] = {};

  for (int it = 0; it < SEQ / 64; ++it) {
    const int cur = it & 1;
    if (it < SEQ / 64 - 1) {
#pragma unroll
      for (int i = 0; i < 4; i++) gload_lds16(kg[i], &Ks[cur ^ 1][klofs[i]]);
#pragma unroll
      for (int i = 0; i < 4; i++) gload_lds16(vg[i], &Vs[cur ^ 1][vlofs[i]]);
#pragma unroll
      for (int i = 0; i < 4; i++) { kg[i] += 64 * QSTRIDE; vg[i] += 64; }
    }

    const unsigned short* kb = &Ks[cur][0];
    f32x4 sacc[2][4] = {};
#pragma unroll
    for (int js = 0; js < 4; js++)
#pragma unroll
      for (int kc = 0; kc < 4; kc++) {
        bf16x8 kf = *(const bf16x8*)(kb + (js * 16 + l15) * 128 + (((kc * 4 + quad) ^ l15) * 8));
        sacc[0][js] = __builtin_amdgcn_mfma_f32_16x16x32_bf16(kf, qf[0][kc], sacc[0][js], 0, 0, 0);
        sacc[1][js] = __builtin_amdgcn_mfma_f32_16x16x32_bf16(kf, qf[1][kc], sacc[1][js], 0, 0, 0);
      }

    f16x4 pb[2][4];
#pragma unroll
    for (int t = 0; t < 2; t++)
#pragma unroll
      for (int js = 0; js < 4; js++)
#pragma unroll
        for (int r = 0; r < 4; r++) {
          float p = fast_exp2(sacc[t][js][r] * SCALE_LOG2E);
          lsum[t] += p;
          pb[t][js][r] = (_Float16)p;
        }

    const unsigned short* vb_ = &Vs[cur][0];
#pragma unroll
    for (int jt = 0; jt < 8; jt++)
#pragma unroll
      for (int js = 0; js < 4; js++) {
        f16x4 vf = *(const f16x4*)(vb_ + (jt * 16 + l15) * 64 +
                                   (((js * 2 + (quad >> 1)) ^ (lane & 7)) * 8) + (quad & 1) * 4);
        Oa[0][jt] = __builtin_amdgcn_mfma_f32_16x16x16f16(vf, pb[0][js], Oa[0][jt], 0, 0, 0);
        Oa[1][jt] = __builtin_amdgcn_mfma_f32_16x16x16f16(vf, pb[1][js], Oa[1][jt], 0, 0, 0);
      }

    __builtin_amdgcn_s_waitcnt(0);
    __syncthreads();
  }

  float inv[2];
#pragma unroll
  for (int t = 0; t < 2; t++) {
    float s = lsum[t];
    s += __shfl_xor(s, 16);
    s += __shfl_xor(s, 32);
    inv[t] = 1.0f / s;
  }

#pragma unroll
  for (int t = 0; t < 2; t++) {
    const size_t rowbase = (size_t)(b * SEQ + q0 + wave * 32 + t * 16 + l15) * D_MODEL + h * HD;
#pragma unroll
    for (int jt = 0; jt < 8; jt++) {
      ushort4 o;
      o.x = f2bf(Oa[t][jt][0] * inv[t]);
      o.y = f2bf(Oa[t][jt][1] * inv[t]);
      o.z = f2bf(Oa[t][jt][2] * inv[t]);
      o.w = f2bf(Oa[t][jt][3] * inv[t]);
      *(ushort4*)(Og + rowbase + jt * 16 + quad * 4) = o;
    }
  }
}

// ---------------- launcher ----------------
extern "C" void kernel_launch(void* const* d_in, const int* in_sizes, int n_in,
                              void* d_out, int out_size, void* d_ws, size_t ws_size,
                              hipStream_t stream) {
  const float* x = (const float*)d_in[0];
  const float* wq = (const float*)d_in[1];
  const float* wk = (const float*)d_in[2];
  const float* wv = (const float*)d_in[3];
  const float* wo = (const float*)d_in[4];
  float* out = (float*)d_out;
  char* ws = (char*)d_ws;
  const size_t MB = 1u << 20;
  if (ws_size < 96 * MB) return;

  unsigned short* xb = (unsigned short*)(ws);             // 16 MB (reused as Ab)
  unsigned short* wqkv = (unsigned short*)(ws + 16 * MB); // 24 MB [6144,2048]
  unsigned short* wob = (unsigned short*)(ws + 40 * MB);  // 8 MB
  unsigned short* QKb = (unsigned short*)(ws + 48 * MB);  // 32 MB [4096,4096]
  unsigned short* Vtb = (unsigned short*)(ws + 80 * MB);  // 16 MB f16
  unsigned short* Ab = xb;

  static int lds_set = 0;
  if (!lds_set) {
    hipFuncSetAttribute((const void*)gemm_qkv,
                        hipFuncAttributeMaxDynamicSharedMemorySize, 147456);
    hipFuncSetAttribute((const void*)gemm_out,
                        hipFuncAttributeMaxDynamicSharedMemorySize, 147456);
    lds_set = 1;
  }

  cvt_all<<<dim3(8192, 5), 256, 0, stream>>>(x, wq, wk, wv, wo, xb, wqkv, wob);

  gemm_qkv<<<768, 512, 147456, stream>>>(xb, wqkv, QKb, Vtb);

  flash_attn<<<512, 256, 0, stream>>>(QKb, Vtb, Ab);

  gemm_out<<<256, 512, 147456, stream>>>(Ab, wob, out);
}

// Round 3
// 355.545 us; speedup vs baseline: 1.1173x; 1.0123x over previous
//
#include <hip/hip_runtime.h>

#define D_MODEL 2048
#define SEQ 2048
#define BATCH 2
#define NH 16
#define HD 128
#define MTOT 4096   // BATCH*SEQ
#define NQKV 6144   // 3*D_MODEL
#define QSTRIDE 4096  // QK buffer row stride (Q cols 0..2047, K cols 2048..4095)

// 1/sqrt(128) * log2(e)
static constexpr float SCALE_LOG2E = 0.08838834764831845f * 1.4426950408889634f;

typedef __bf16 bf16x8 __attribute__((ext_vector_type(8)));
typedef _Float16 f16x4 __attribute__((ext_vector_type(4)));
typedef float f32x4 __attribute__((ext_vector_type(4)));

__device__ inline unsigned short f2bf(float f) {
  unsigned int u = __builtin_bit_cast(unsigned int, f);
  u += 0x7fffu + ((u >> 16) & 1u);
  return (unsigned short)(u >> 16);
}

__device__ inline float fast_exp2(float x) {
#if __has_builtin(__builtin_amdgcn_exp2f)
  return __builtin_amdgcn_exp2f(x);
#else
  return exp2f(x);
#endif
}

__device__ inline void gload_lds16(const void* g, void* s) {
  __builtin_amdgcn_global_load_lds(
      (__attribute__((address_space(1))) void*)g,
      (__attribute__((address_space(3))) void*)s, 16, 0, 0);
}

#define BARX() __builtin_amdgcn_s_barrier()
#define PRIO(x) __builtin_amdgcn_s_setprio(x)
#define LGK0()                                              \
  do {                                                      \
    asm volatile("s_waitcnt lgkmcnt(0)" ::: "memory");      \
    __builtin_amdgcn_sched_barrier(0);                      \
  } while (0)
#define VMW(n) asm volatile("s_waitcnt vmcnt(" #n ")" ::: "memory")

// ---------------- fused fp32 -> bf16 conversion (all 5 inputs) -------------
__global__ __launch_bounds__(256) void cvt_all(
    const float* __restrict__ x, const float* __restrict__ wq,
    const float* __restrict__ wk, const float* __restrict__ wv,
    const float* __restrict__ wo, unsigned short* __restrict__ xb,
    unsigned short* __restrict__ wqkv, unsigned short* __restrict__ wob) {
  const int y = blockIdx.y;
  const float* src;
  unsigned short* dst;
  int n4;
  if (y == 0) { src = x; dst = xb; n4 = MTOT * D_MODEL / 4; }
  else if (y == 4) { src = wo; dst = wob; n4 = D_MODEL * D_MODEL / 4; }
  else {
    src = (y == 1) ? wq : (y == 2) ? wk : wv;
    dst = wqkv + (size_t)(y - 1) * D_MODEL * D_MODEL;
    n4 = D_MODEL * D_MODEL / 4;
  }
  int i = blockIdx.x * 256 + threadIdx.x;
  if (i < n4) {
    float4 v = ((const float4*)src)[i];
    ushort4 o;
    o.x = f2bf(v.x); o.y = f2bf(v.y); o.z = f2bf(v.z); o.w = f2bf(v.w);
    ((ushort4*)dst)[i] = o;
  }
}

// ============================================================================
// gemm_qk: C[4096,4096] = A[4096,2048] * B[4096,2048]^T -> bf16 QK buffer.
// m201 geometry: BM=BN=256, BK=64, 8 waves (2M x 4N -> 128x64/wave),
// double-buffered LDS (2 x 64KB), 4 phases per K-tile (16 MFMA each),
// counted vmcnt: B-units staged ph0/ph1, A-lo ph2, A-hi ph3;
// vmcnt(4) end-of-ph1 proves A-hi of current tile, vmcnt(2) end-of-tile
// proves B+A-lo of next tile.  Grid 256 blocks = 1 exact round.
// LDS swizzle: 16B chunk slot ^= row&7, applied via pre-swizzled global
// source (linear global_load_lds dest); frag reads un-swizzle.
// ============================================================================
__global__ __launch_bounds__(512, 2) void gemm_qk(
    const unsigned short* __restrict__ A, const unsigned short* __restrict__ B,
    unsigned short* __restrict__ QK) {
  extern __shared__ __align__(16) char smem[];
  const int tid = threadIdx.x;
  const int lane = tid & 63;
  const int wave = tid >> 6;
  const int quad = lane >> 4;
  const int l15 = lane & 15;
  const int bid = blockIdx.x;
  const int wgid = (bid & 7) * 32 + (bid >> 3);  // bijective XCD swizzle
  const int tm = wgid >> 4, tn = wgid & 15;
  const int m0 = tm * 256, n0 = tn * 256;
  const int wm = wave >> 2;  // 0..1
  const int wn = wave & 3;   // 0..3

  const unsigned short* Ag = A + (size_t)(m0 + wave * 8 + (lane >> 3)) * 2048 +
                             (((lane & 7) ^ (lane >> 3)) * 8);
  const unsigned short* Bg = B + (size_t)(n0 + wave * 8 + (lane >> 3)) * 2048 +
                             (((lane & 7) ^ (lane >> 3)) * 8);
  char* sd = smem + wave * 1024;

  const int arow0 = (wm * 128 + l15) * 128;  // byte base, A frag (mh=0,mi=0)
  const int brow0 = (wn * 64 + l15) * 128;
  const int sk0 = (quad ^ (l15 & 7)) * 16;
  const int sk1 = ((4 + quad) ^ (l15 & 7)) * 16;

  f32x4 acc[8][4] = {};
  bf16x8 a[4][2], bl[2][2], bh[2][2];

#define QSA(u, nb, ko) \
  gload_lds16(Ag + (size_t)(u) * 64 * 2048 + (ko), sd + (nb) * 65536 + (u) * 8192)
#define QSB(u, nb, ko) \
  gload_lds16(Bg + (size_t)(u) * 64 * 2048 + (ko), sd + (nb) * 65536 + 32768 + (u) * 8192)
#define QRA(mh, cb)                                                               \
  _Pragma("unroll") for (int mi = 0; mi < 4; mi++) {                              \
    a[mi][0] = *(const bf16x8*)(smem + (cb) * 65536 + arow0 + ((mh) * 64 + mi * 16) * 128 + sk0); \
    a[mi][1] = *(const bf16x8*)(smem + (cb) * 65536 + arow0 + ((mh) * 64 + mi * 16) * 128 + sk1); \
  }
#define QRB(dst, nh, cb)                                                          \
  _Pragma("unroll") for (int ni = 0; ni < 2; ni++) {                              \
    dst[ni][0] = *(const bf16x8*)(smem + (cb) * 65536 + 32768 + brow0 + ((nh) * 32 + ni * 16) * 128 + sk0); \
    dst[ni][1] = *(const bf16x8*)(smem + (cb) * 65536 + 32768 + brow0 + ((nh) * 32 + ni * 16) * 128 + sk1); \
  }
#define QMM(mh, bsrc, nh)                                                         \
  _Pragma("unroll") for (int mi = 0; mi < 4; mi++)                                \
  _Pragma("unroll") for (int ni = 0; ni < 2; ni++) {                              \
    acc[(mh) * 4 + mi][(nh) * 2 + ni] = __builtin_amdgcn_mfma_f32_16x16x32_bf16(  \
        a[mi][0], bsrc[ni][0], acc[(mh) * 4 + mi][(nh) * 2 + ni], 0, 0, 0);       \
    acc[(mh) * 4 + mi][(nh) * 2 + ni] = __builtin_amdgcn_mfma_f32_16x16x32_bf16(  \
        a[mi][1], bsrc[ni][1], acc[(mh) * 4 + mi][(nh) * 2 + ni], 0, 0, 0);       \
  }

  // prologue: tile 0 fully staged (B0..B3, A0, A2, A1, A3), proven.
  QSB(0, 0, 0); QSB(1, 0, 0); QSB(2, 0, 0); QSB(3, 0, 0);
  QSA(0, 0, 0); QSA(2, 0, 0); QSA(1, 0, 0); QSA(3, 0, 0);
  VMW(0);
  BARX();

#define QKTILE(t, cb, nb)                                                         \
  {                                                                               \
    const int ko = (((t) + 1) & 31) * 64;                                         \
    /* ph0 */                                                                     \
    QRA(0, cb); QRB(bl, 0, cb);                                                   \
    QSB(0, nb, ko); QSB(1, nb, ko);                                               \
    BARX(); LGK0(); PRIO(1); QMM(0, bl, 0); PRIO(0); BARX();                      \
    /* ph1 */                                                                     \
    QRB(bh, 1, cb);                                                               \
    QSB(2, nb, ko); QSB(3, nb, ko);                                               \
    BARX(); LGK0(); PRIO(1); QMM(0, bh, 1); PRIO(0); VMW(4); BARX();              \
    /* ph2 */                                                                     \
    QRA(1, cb);                                                                   \
    QSA(0, nb, ko); QSA(2, nb, ko);                                               \
    BARX(); LGK0(); PRIO(1); QMM(1, bl, 0); PRIO(0); BARX();                      \
    /* ph3 */                                                                     \
    QSA(1, nb, ko); QSA(3, nb, ko);                                               \
    PRIO(1); QMM(1, bh, 1); PRIO(0); VMW(2); BARX();                              \
  }

  for (int t = 0; t < 32; t += 2) {
    QKTILE(t, 0, 1);
    QKTILE(t + 1, 1, 0);
  }

  // epilogue: bf16 stores, row stride 4096
#pragma unroll
  for (int mi = 0; mi < 8; mi++)
#pragma unroll
    for (int ni = 0; ni < 4; ni++) {
      const int mm = m0 + wm * 128 + mi * 16 + quad * 4;
      const int nn = n0 + wn * 64 + ni * 16 + l15;
#pragma unroll
      for (int r = 0; r < 4; r++)
        QK[(size_t)(mm + r) * QSTRIDE + nn] = f2bf(acc[mi][ni][r]);
    }
#undef QSA
#undef QSB
#undef QRA
#undef QRB
#undef QMM
#undef QKTILE
}

// ============================================================================
// Shared 128x256 core for gemm_v / gemm_out: BM=128, BN=256, BK=64,
// 8 waves (4M x 2N -> 32x128/wave, acc=64 VGPR), TRIPLE-buffered LDS
// (3 x 48KB), 2 phases per K-tile (16 MFMA each), stage tile t+2 during t,
// single vmcnt(6) per tile (2-tile latency cover).  Grid 256 = 1 round.
// ============================================================================
#define VCORE_BODY(Aptr, Bptr)                                                    \
  const int tid = threadIdx.x;                                                    \
  const int lane = tid & 63;                                                      \
  const int wave = tid >> 6;                                                      \
  const int quad = lane >> 4;                                                     \
  const int l15 = lane & 15;                                                      \
  const int bid = blockIdx.x;                                                     \
  const int wgid = (bid & 7) * 32 + (bid >> 3);                                   \
  const int tm = wgid >> 3, tn = wgid & 7;                                        \
  const int m0 = tm * 128, n0 = tn * 256;                                         \
  const int wm = wave >> 1; /* 0..3 */                                            \
  const int wn = wave & 1;  /* 0..1 */                                            \
  const unsigned short* Ag = (Aptr) + (size_t)(m0 + wave * 8 + (lane >> 3)) * 2048 + \
                             (((lane & 7) ^ (lane >> 3)) * 8);                    \
  const unsigned short* Bg = (Bptr) + (size_t)(n0 + wave * 8 + (lane >> 3)) * 2048 + \
                             (((lane & 7) ^ (lane >> 3)) * 8);                    \
  char* sd = smem + wave * 1024;                                                  \
  const int arow0 = (wm * 32 + l15) * 128;                                        \
  const int brow0 = (wn * 128 + l15) * 128;                                       \
  const int sk0 = (quad ^ (l15 & 7)) * 16;                                        \
  const int sk1 = ((4 + quad) ^ (l15 & 7)) * 16;                                  \
  f32x4 acc[2][8] = {};                                                           \
  bf16x8 a[2][2], bl[4][2], bh[4][2];

#define VSA(u, nb, ko) \
  gload_lds16(Ag + (size_t)(u) * 64 * 2048 + (ko), sd + (nb) * 49152 + (u) * 8192)
#define VSB(u, nb, ko) \
  gload_lds16(Bg + (size_t)(u) * 64 * 2048 + (ko), sd + (nb) * 49152 + 16384 + (u) * 8192)
#define VRA(cb)                                                                   \
  _Pragma("unroll") for (int mi = 0; mi < 2; mi++) {                              \
    a[mi][0] = *(const bf16x8*)(smem + (cb) * 49152 + arow0 + mi * 2048 + sk0);   \
    a[mi][1] = *(const bf16x8*)(smem + (cb) * 49152 + arow0 + mi * 2048 + sk1);   \
  }
#define VRB(dst, nh, cb)                                                          \
  _Pragma("unroll") for (int ni = 0; ni < 4; ni++) {                              \
    dst[ni][0] = *(const bf16x8*)(smem + (cb) * 49152 + 16384 + brow0 + ((nh) * 64 + ni * 16) * 128 + sk0); \
    dst[ni][1] = *(const bf16x8*)(smem + (cb) * 49152 + 16384 + brow0 + ((nh) * 64 + ni * 16) * 128 + sk1); \
  }
#define VMM(bsrc, nh)                                                             \
  _Pragma("unroll") for (int mi = 0; mi < 2; mi++)                                \
  _Pragma("unroll") for (int ni = 0; ni < 4; ni++) {                              \
    acc[mi][(nh) * 4 + ni] = __builtin_amdgcn_mfma_f32_16x16x32_bf16(             \
        a[mi][0], bsrc[ni][0], acc[mi][(nh) * 4 + ni], 0, 0, 0);                  \
    acc[mi][(nh) * 4 + ni] = __builtin_amdgcn_mfma_f32_16x16x32_bf16(             \
        a[mi][1], bsrc[ni][1], acc[mi][(nh) * 4 + ni], 0, 0, 0);                  \
  }
#define VSTAGE6(nb, ko)                                                           \
  VSA(0, nb, ko); VSA(1, nb, ko); VSB(0, nb, ko);                                 \
  VSB(1, nb, ko); VSB(2, nb, ko); VSB(3, nb, ko);

#define VTILE(t, cb, nb)                                                          \
  {                                                                               \
    const int ko = (((t) + 2) & 31) * 64;                                         \
    /* ph0 */                                                                     \
    VRA(cb); VRB(bl, 0, cb);                                                      \
    VSA(0, nb, ko); VSA(1, nb, ko); VSB(0, nb, ko);                               \
    BARX(); LGK0(); PRIO(1); VMM(bl, 0); PRIO(0); BARX();                         \
    /* ph1 */                                                                     \
    VRB(bh, 1, cb);                                                               \
    VSB(1, nb, ko); VSB(2, nb, ko); VSB(3, nb, ko);                               \
    BARX(); LGK0(); PRIO(1); VMM(bh, 1); PRIO(0); VMW(6); BARX();                 \
  }

#define VCORE_LOOP()                                                              \
  VSTAGE6(0, 0);                                                                  \
  VSTAGE6(1, 64);                                                                 \
  VMW(6);                                                                         \
  BARX();                                                                         \
  for (int t = 0; t < 30; t += 3) {                                               \
    VTILE(t + 0, 0, 2);                                                           \
    VTILE(t + 1, 1, 0);                                                           \
    VTILE(t + 2, 2, 1);                                                           \
  }                                                                               \
  VTILE(30, 0, 2);                                                                \
  VTILE(31, 1, 0);

// ---------------- V-projection GEMM -> transposed f16 Vt[bh][d][s] ---------
__global__ __launch_bounds__(512, 2) void gemm_v(
    const unsigned short* __restrict__ A, const unsigned short* __restrict__ B,
    unsigned short* __restrict__ Vt) {
  extern __shared__ __align__(16) char smem[];
  VCORE_BODY(A, B);
  VCORE_LOOP();

  // transpose via LDS: T[2 heads][128 d][136 s-pad] f16
  VMW(0);
  BARX();
  unsigned short* T = (unsigned short*)smem;
  const int h0 = n0 >> 7;  // = tn*2
  const int bb = m0 >> 11;
  const int sbase = m0 & (SEQ - 1);
#pragma unroll
  for (int mi = 0; mi < 2; mi++)
#pragma unroll
    for (int q = 0; q < 8; q++) {
      const int d = q * 16 + l15;
      const int slocal = wm * 32 + mi * 16 + quad * 4;
      f16x4 hv;
#pragma unroll
      for (int r = 0; r < 4; r++) hv[r] = (_Float16)acc[mi][q][r];
      *(f16x4*)(T + wn * 17408 + d * 136 + slocal) = hv;
    }
  BARX();
  const int hd2 = tid >> 8;          // 0..1
  const int d = (tid >> 1) & 127;
  const int sc = (tid & 1) * 64;
  const size_t vrow = ((size_t)((bb * NH + h0 + hd2) * HD + d)) * SEQ + sbase + sc;
#pragma unroll
  for (int j = 0; j < 8; j++) {
    float4 c4 = *(const float4*)(T + hd2 * 17408 + d * 136 + sc + j * 8);
    *(float4*)(Vt + vrow + j * 8) = c4;
  }
}

// ---------------- output-projection GEMM -> f32 C ---------------------------
__global__ __launch_bounds__(512, 2) void gemm_out(
    const unsigned short* __restrict__ A, const unsigned short* __restrict__ B,
    float* __restrict__ C) {
  extern __shared__ __align__(16) char smem[];
  VCORE_BODY(A, B);
  VCORE_LOOP();

#pragma unroll
  for (int mi = 0; mi < 2; mi++)
#pragma unroll
    for (int q = 0; q < 8; q++) {
      const int mm = m0 + wm * 32 + mi * 16 + quad * 4;
      const int nn = n0 + wn * 128 + q * 16 + l15;
#pragma unroll
      for (int r = 0; r < 4; r++)
        C[(size_t)(mm + r) * D_MODEL + nn] = acc[mi][q][r];
    }
}

// ---------------- flash attention v3 (XCD-swizzled) ------------------------
__global__ __launch_bounds__(256, 2) void flash_attn(
    const unsigned short* __restrict__ QK, const unsigned short* __restrict__ Vt,
    unsigned short* __restrict__ Og) {
  __shared__ __align__(16) unsigned short Ks[2][64 * 128];
  __shared__ __align__(16) unsigned short Vs[2][128 * 64];
  const int tid = threadIdx.x;
  const int lane = tid & 63;
  const int wave = tid >> 6;
  const int quad = lane >> 4;
  const int l15 = lane & 15;
  const int id = blockIdx.x;
  const int xr = id & 7;
  const int kk = id >> 3;
  const int bh = xr * 4 + (kk >> 4);
  const int b = bh >> 4, h = bh & 15;
  const int q0 = (kk & 15) * 128;

  const size_t kbase = (size_t)(b * SEQ) * QSTRIDE + D_MODEL + h * HD;
  const size_t vbase = (size_t)bh * HD * SEQ;

  bf16x8 qf[2][4];
#pragma unroll
  for (int t = 0; t < 2; t++)
#pragma unroll
    for (int kc = 0; kc < 4; kc++)
      qf[t][kc] = *(const bf16x8*)(QK + (size_t)(b * SEQ + q0 + wave * 32 + t * 16 + l15) * QSTRIDE +
                                   h * HD + kc * 32 + quad * 8);

  const unsigned short* kg[4];
  const unsigned short* vg[4];
  int klofs[4], vlofs[4];
#pragma unroll
  for (int i = 0; i < 4; i++) {
    int krow = wave * 16 + i * 4 + quad;
    int kc_ = l15 ^ (i * 4 + quad);
    kg[i] = QK + kbase + (size_t)krow * QSTRIDE + kc_ * 8;
    klofs[i] = (wave * 16 + i * 4) * 128;
    int vrow = wave * 32 + i * 8 + (lane >> 3);
    int vc_ = (lane & 7) ^ (lane >> 3);
    vg[i] = Vt + vbase + (size_t)vrow * SEQ + vc_ * 8;
    vlofs[i] = (wave * 32 + i * 8) * 64;
  }

#pragma unroll
  for (int i = 0; i < 4; i++) gload_lds16(kg[i], &Ks[0][klofs[i]]);
#pragma unroll
  for (int i = 0; i < 4; i++) gload_lds16(vg[i], &Vs[0][vlofs[i]]);
#pragma unroll
  for (int i = 0; i < 4; i++) { kg[i] += 64 * QSTRIDE; vg[i] += 64; }
  __builtin_amdgcn_s_waitcnt(0);
  __syncthreads();

  float lsum[2] = {0.f, 0.f};
  f32x4 Oa[2][8] = {};

  for (int it = 0; it < SEQ / 64; ++it) {
    const int cur = it & 1;
    if (it < SEQ / 64 - 1) {
#pragma unroll
      for (int i = 0; i < 4; i++) gload_lds16(kg[i], &Ks[cur ^ 1][klofs[i]]);
#pragma unroll
      for (int i = 0; i < 4; i++) gload_lds16(vg[i], &Vs[cur ^ 1][vlofs[i]]);
#pragma unroll
      for (int i = 0; i < 4; i++) { kg[i] += 64 * QSTRIDE; vg[i] += 64; }
    }

    const unsigned short* kb = &Ks[cur][0];
    f32x4 sacc[2][4] = {};
#pragma unroll
    for (int js = 0; js < 4; js++)
#pragma unroll
      for (int kc = 0; kc < 4; kc++) {
        bf16x8 kf = *(const bf16x8*)(kb + (js * 16 + l15) * 128 + (((kc * 4 + quad) ^ l15) * 8));
        sacc[0][js] = __builtin_amdgcn_mfma_f32_16x16x32_bf16(kf, qf[0][kc], sacc[0][js], 0, 0, 0);
        sacc[1][js] = __builtin_amdgcn_mfma_f32_16x16x32_bf16(kf, qf[1][kc], sacc[1][js], 0, 0, 0);
      }

    f16x4 pb[2][4];
#pragma unroll
    for (int t = 0; t < 2; t++)
#pragma unroll
      for (int js = 0; js < 4; js++)
#pragma unroll
        for (int r = 0; r < 4; r++) {
          float p = fast_exp2(sacc[t][js][r] * SCALE_LOG2E);
          lsum[t] += p;
          pb[t][js][r] = (_Float16)p;
        }

    const unsigned short* vb_ = &Vs[cur][0];
#pragma unroll
    for (int jt = 0; jt < 8; jt++)
#pragma unroll
      for (int js = 0; js < 4; js++) {
        f16x4 vf = *(const f16x4*)(vb_ + (jt * 16 + l15) * 64 +
                                   (((js * 2 + (quad >> 1)) ^ (lane & 7)) * 8) + (quad & 1) * 4);
        Oa[0][jt] = __builtin_amdgcn_mfma_f32_16x16x16f16(vf, pb[0][js], Oa[0][jt], 0, 0, 0);
        Oa[1][jt] = __builtin_amdgcn_mfma_f32_16x16x16f16(vf, pb[1][js], Oa[1][jt], 0, 0, 0);
      }

    __builtin_amdgcn_s_waitcnt(0);
    __syncthreads();
  }

  float inv[2];
#pragma unroll
  for (int t = 0; t < 2; t++) {
    float s = lsum[t];
    s += __shfl_xor(s, 16);
    s += __shfl_xor(s, 32);
    inv[t] = 1.0f / s;
  }

#pragma unroll
  for (int t = 0; t < 2; t++) {
    const size_t rowbase = (size_t)(b * SEQ + q0 + wave * 32 + t * 16 + l15) * D_MODEL + h * HD;
#pragma unroll
    for (int jt = 0; jt < 8; jt++) {
      ushort4 o;
      o.x = f2bf(Oa[t][jt][0] * inv[t]);
      o.y = f2bf(Oa[t][jt][1] * inv[t]);
      o.z = f2bf(Oa[t][jt][2] * inv[t]);
      o.w = f2bf(Oa[t][jt][3] * inv[t]);
      *(ushort4*)(Og + rowbase + jt * 16 + quad * 4) = o;
    }
  }
}

// ---------------- launcher ----------------
extern "C" void kernel_launch(void* const* d_in, const int* in_sizes, int n_in,
                              void* d_out, int out_size, void* d_ws, size_t ws_size,
                              hipStream_t stream) {
  const float* x = (const float*)d_in[0];
  const float* wq = (const float*)d_in[1];
  const float* wk = (const float*)d_in[2];
  const float* wv = (const float*)d_in[3];
  const float* wo = (const float*)d_in[4];
  float* out = (float*)d_out;
  char* ws = (char*)d_ws;
  const size_t MB = 1u << 20;
  if (ws_size < 96 * MB) return;

  unsigned short* xb = (unsigned short*)(ws);             // 16 MB (reused as Ab)
  unsigned short* wqkv = (unsigned short*)(ws + 16 * MB); // 24 MB [6144,2048]
  unsigned short* wob = (unsigned short*)(ws + 40 * MB);  // 8 MB
  unsigned short* QKb = (unsigned short*)(ws + 48 * MB);  // 32 MB [4096,4096]
  unsigned short* Vtb = (unsigned short*)(ws + 80 * MB);  // 16 MB f16
  unsigned short* Ab = xb;

  static int lds_set = 0;
  if (!lds_set) {
    hipFuncSetAttribute((const void*)gemm_qk,
                        hipFuncAttributeMaxDynamicSharedMemorySize, 131072);
    hipFuncSetAttribute((const void*)gemm_v,
                        hipFuncAttributeMaxDynamicSharedMemorySize, 147456);
    hipFuncSetAttribute((const void*)gemm_out,
                        hipFuncAttributeMaxDynamicSharedMemorySize, 147456);
    lds_set = 1;
  }

  cvt_all<<<dim3(8192, 5), 256, 0, stream>>>(x, wq, wk, wv, wo, xb, wqkv, wob);

  gemm_qk<<<256, 512, 131072, stream>>>(xb, wqkv, QKb);
  gemm_v<<<256, 512, 147456, stream>>>(xb, wqkv + (size_t)4096 * 2048, Vtb);

  flash_attn<<<512, 256, 0, stream>>>(QKb, Vtb, Ab);

  gemm_out<<<256, 512, 147456, stream>>>(Ab, wob, out);
}